// Round 7
// baseline (350.120 us; speedup 1.0000x reference)
//
#include <hip/hip_runtime.h>
#include <math.h>

typedef unsigned short u16;
typedef unsigned int   u32;
typedef __bf16  bf16x8 __attribute__((ext_vector_type(8)));
typedef short   s16x4  __attribute__((ext_vector_type(4)));
typedef float   f32x4  __attribute__((ext_vector_type(4)));

#define B_  4
#define T_  2048
#define D_  1024
#define H_  16
#define HD_ 64
#define M_  (B_*T_)   // 8192
#define NEG_BIG (-30000.0f)

__device__ __forceinline__ float bf2f(u16 h) {
    u32 u = ((u32)h) << 16;
    return __uint_as_float(u);
}
__device__ __forceinline__ u16 f2bf(float f) {
    u32 u = __float_as_uint(f);
    u32 r = (u + 0x7fffu + ((u >> 16) & 1u)) >> 16;
    return (u16)r;
}
__device__ __forceinline__ void async_copy16(const u16* g, u16* l) {
    __builtin_amdgcn_global_load_lds(
        (const __attribute__((address_space(1))) u32*)g,
        (__attribute__((address_space(3))) u32*)l, 16, 0, 0);
}

// ---------------------------------------------------------------------------
// x (fp32) -> bf16, vectorized. 8 elements/thread.
// ---------------------------------------------------------------------------
__global__ __launch_bounds__(256)
void convert_x(const float* __restrict__ X, u16* __restrict__ Xb)
{
    const int id = (blockIdx.x * 256 + threadIdx.x) * 8;
    float4 f0 = *(const float4*)(X + id);
    float4 f1 = *(const float4*)(X + id + 4);
    union { u16 t[8]; uint4 v; } c;
    c.t[0] = f2bf(f0.x); c.t[1] = f2bf(f0.y); c.t[2] = f2bf(f0.z); c.t[3] = f2bf(f0.w);
    c.t[4] = f2bf(f1.x); c.t[5] = f2bf(f1.y); c.t[6] = f2bf(f1.z); c.t[7] = f2bf(f1.w);
    *(uint4*)(Xb + id) = c.v;
}

// ---------------------------------------------------------------------------
// bf16 MFMA GEMM, B^T layout, m97 structure (unchanged).
// ---------------------------------------------------------------------------
template<int OUT_F32>
__global__ __launch_bounds__(256)
void gemm_bt(const u16* __restrict__ A, const u16* __restrict__ Bt_base,
             const float* __restrict__ bias0, const float* __restrict__ bias1,
             const float* __restrict__ bias2,
             void* __restrict__ C_base, int M, int N, int K)
{
    const int z = blockIdx.z;
    const u16* Bt  = Bt_base + (size_t)z * N * K;
    const float* bias = (z == 0) ? bias0 : ((z == 1) ? bias1 : bias2);

    const int m0 = blockIdx.x * 128, n0 = blockIdx.y * 128;
    const int tid = threadIdx.x, lane = tid & 63, wave = tid >> 6;
    const int wm = (wave >> 1) * 64, wn = (wave & 1) * 64;
    const int quad = lane >> 4, l16 = lane & 15;

    __shared__ __align__(16) u16 As[128 * 32];
    __shared__ __align__(16) u16 Bs[128 * 32];

    f32x4 acc[4][4];
#pragma unroll
    for (int i = 0; i < 4; i++)
#pragma unroll
        for (int j = 0; j < 4; j++) acc[i][j] = (f32x4){0.f, 0.f, 0.f, 0.f};

    for (int k0 = 0; k0 < K; k0 += 32) {
        __syncthreads();
#pragma unroll
        for (int i = 0; i < 2; i++) {
            int idx = i * 256 + tid;
            int r = idx >> 2, c = (idx & 3) * 8;
            async_copy16(A  + (size_t)(m0 + r) * K + k0 + c, &As[idx * 8]);
            async_copy16(Bt + (size_t)(n0 + r) * K + k0 + c, &Bs[idx * 8]);
        }
        __syncthreads();

        bf16x8 af[4], bfr[4];
#pragma unroll
        for (int mi = 0; mi < 4; mi++)
            af[mi] = *(const bf16x8*)&As[(wm + mi * 16 + l16) * 32 + quad * 8];
#pragma unroll
        for (int ni = 0; ni < 4; ni++)
            bfr[ni] = *(const bf16x8*)&Bs[(wn + ni * 16 + l16) * 32 + quad * 8];
#pragma unroll
        for (int mi = 0; mi < 4; mi++)
#pragma unroll
            for (int ni = 0; ni < 4; ni++)
                acc[mi][ni] = __builtin_amdgcn_mfma_f32_16x16x32_bf16(
                    af[mi], bfr[ni], acc[mi][ni], 0, 0, 0);
    }

    float bv[4];
#pragma unroll
    for (int ni = 0; ni < 4; ni++) bv[ni] = bias[n0 + wn + ni * 16 + l16];
#pragma unroll
    for (int mi = 0; mi < 4; mi++) {
#pragma unroll
        for (int reg = 0; reg < 4; reg++) {
            int row = m0 + wm + mi * 16 + quad * 4 + reg;
#pragma unroll
            for (int ni = 0; ni < 4; ni++) {
                int col = n0 + wn + ni * 16 + l16;
                float v = acc[mi][ni][reg] + bv[ni];
                if (OUT_F32)
                    ((float*)C_base + (size_t)z * M * N)[(size_t)row * N + col] = v;
                else
                    ((u16*)C_base + (size_t)z * M * N)[(size_t)row * N + col] = f2bf(v);
            }
        }
    }
}

// ---------------------------------------------------------------------------
// Transpose + convert fp32 weight (D x D) -> bf16 Wt[n][k] = W[k][n].
// ---------------------------------------------------------------------------
__global__ __launch_bounds__(256)
void transpose_w(const float* __restrict__ w0, const float* __restrict__ w1,
                 const float* __restrict__ w2,
                 u16* __restrict__ out)
{
    const int z = blockIdx.z;
    const float* W = (z == 0) ? w0 : ((z == 1) ? w1 : w2);
    u16* Wt = out + (size_t)z * D_ * D_;
    const int k0 = blockIdx.x * 64, n0 = blockIdx.y * 64;
    __shared__ u16 tl[64][72];
    const int tid = threadIdx.x;
    const int r = tid >> 2, c4 = (tid & 3) * 16;
#pragma unroll
    for (int j = 0; j < 4; j++) {
        float4 fv = *(const float4*)(W + (size_t)(k0 + r) * D_ + n0 + c4 + j * 4);
        tl[r][c4 + j * 4 + 0] = f2bf(fv.x);
        tl[r][c4 + j * 4 + 1] = f2bf(fv.y);
        tl[r][c4 + j * 4 + 2] = f2bf(fv.z);
        tl[r][c4 + j * 4 + 3] = f2bf(fv.w);
    }
    __syncthreads();
    u16 vals[16];
#pragma unroll
    for (int j = 0; j < 16; j++) vals[j] = tl[c4 + j][r];
#pragma unroll
    for (int j = 0; j < 2; j++)
        *(uint4*)(Wt + (size_t)(n0 + r) * D_ + k0 + c4 + j * 8) =
            *(const uint4*)&vals[j * 8];
}

// ---------------------------------------------------------------------------
// Transpose V (B,T,H,HD) bf16 -> Vt (B,H,HD,T) bf16
// ---------------------------------------------------------------------------
__global__ __launch_bounds__(256)
void transpose_v(const u16* __restrict__ V, u16* __restrict__ Vt)
{
    const int t0 = blockIdx.x * 64;
    const int h = blockIdx.y, b = blockIdx.z;
    __shared__ u16 tl[64][72];
    const int tid = threadIdx.x;
    const int r = tid >> 2, c4 = (tid & 3) * 16;
    const u16* Vg = V + ((size_t)(b * T_ + t0)) * D_ + h * HD_;
#pragma unroll
    for (int j = 0; j < 2; j++)
        *(uint4*)&tl[r][c4 + j * 8] =
            *(const uint4*)(Vg + (size_t)r * D_ + c4 + j * 8);
    __syncthreads();
    u16 vals[16];
#pragma unroll
    for (int j = 0; j < 16; j++) vals[j] = tl[c4 + j][r];
    u16* Og = Vt + ((size_t)(b * H_ + h)) * HD_ * T_ + (size_t)r * T_ + t0 + c4;
#pragma unroll
    for (int j = 0; j < 2; j++)
        *(uint4*)(Og + j * 8) = *(const uint4*)&vals[j * 8];
}

// ---------------------------------------------------------------------------
// RoPE on Q and K in place (bf16), vectorized (G13).
// ---------------------------------------------------------------------------
__global__ __launch_bounds__(256)
void rope_qk(u16* __restrict__ Q, u16* __restrict__ K,
             const float* __restrict__ cosb, const float* __restrict__ sinb)
{
    int g  = blockIdx.x * 256 + threadIdx.x;     // B*T*H*4 threads total
    int d0 = (g & 3) * 8;
    int h  = (g >> 2) & (H_ - 1);
    int bt = g >> 6;
    int t  = bt & (T_ - 1);
    size_t off = (size_t)bt * D_ + h * HD_ + d0;

    const float* cp = cosb + (size_t)t * HD_ + d0;
    const float* sp = sinb + (size_t)t * HD_ + d0;
    float4 c1a = *(const float4*)(cp);
    float4 c1b = *(const float4*)(cp + 4);
    float4 s1a = *(const float4*)(sp);
    float4 s1b = *(const float4*)(sp + 4);
    float4 c2a = *(const float4*)(cp + 32);
    float4 c2b = *(const float4*)(cp + 36);
    float4 s2a = *(const float4*)(sp + 32);
    float4 s2b = *(const float4*)(sp + 36);
    float c1[8] = {c1a.x,c1a.y,c1a.z,c1a.w,c1b.x,c1b.y,c1b.z,c1b.w};
    float s1[8] = {s1a.x,s1a.y,s1a.z,s1a.w,s1b.x,s1b.y,s1b.z,s1b.w};
    float c2[8] = {c2a.x,c2a.y,c2a.z,c2a.w,c2b.x,c2b.y,c2b.z,c2b.w};
    float s2[8] = {s2a.x,s2a.y,s2a.z,s2a.w,s2b.x,s2b.y,s2b.z,s2b.w};

    {
        union { u16 t[8]; uint4 v; } x1, x2, o1, o2;
        x1.v = *(const uint4*)(Q + off);
        x2.v = *(const uint4*)(Q + off + 32);
#pragma unroll
        for (int j = 0; j < 8; j++) {
            float a = bf2f(x1.t[j]), b = bf2f(x2.t[j]);
            o1.t[j] = f2bf(a * c1[j] - b * s1[j]);
            o2.t[j] = f2bf(b * c2[j] + a * s2[j]);
        }
        *(uint4*)(Q + off)      = o1.v;
        *(uint4*)(Q + off + 32) = o2.v;
    }
    {
        union { u16 t[8]; uint4 v; } x1, x2, o1, o2;
        x1.v = *(const uint4*)(K + off);
        x2.v = *(const uint4*)(K + off + 32);
#pragma unroll
        for (int j = 0; j < 8; j++) {
            float a = bf2f(x1.t[j]), b = bf2f(x2.t[j]);
            o1.t[j] = f2bf(a * c1[j] - b * s1[j]);
            o2.t[j] = f2bf(b * c2[j] + a * s2[j]);
        }
        *(uint4*)(K + off)      = o1.v;
        *(uint4*)(K + off + 32) = o2.v;
    }
}

// ---------------------------------------------------------------------------
// Causal MFMA flash attention, v11 (v10 + VALU trims; math identical):
//  - exp2f -> __builtin_amdgcn_exp2f (raw v_exp_f32; library exp2f without
//    fast-math is ~15-20 inst on the quarter-rate trans pipe -> the 61%
//    VALUBusy in v10's counters).
//  - All LDS-read addressing hoisted: per-lane byte bases (kb0b/kb1b, vbb[8])
//    computed once; kb-loop unrolled 2x so buffer parity is compile-time ->
//    every ds_read is base-reg + immediate offset (0 VALU/read).
//  - fmax as nested triples (v_max3 fusion).
//  Everything else (XCD affinity, LPT order, swapped QK^T, in-register P,
//  dbuf 2-phase, swizzled K/V, defer-max, ones-MFMA l) unchanged from v10.
// ---------------------------------------------------------------------------
__global__ __launch_bounds__(512, 2)
void attn_kernel(const u16* __restrict__ Q, const u16* __restrict__ K,
                 const u16* __restrict__ Vt, u16* __restrict__ O)
{
    const int id = blockIdx.x;
    const int xcd = id & 7, rr = id >> 3;   // rr in 0..127
    const int qb = 15 - (rr >> 3);          // monotone heavy -> light per XCD
    const int hb = xcd + 8 * (rr & 7);      // (b,h) pinned to one XCD
    const int h = hb & 15, b = hb >> 4;
    const int tid = threadIdx.x, lane = tid & 63, wave = tid >> 6;
    const int quad = lane >> 4, l16 = lane & 15;
    const int z3 = l16 & 7;

    __shared__ __align__(16) u16 Ks[2 * 8192];   // 32 KB dbuf [128 row][64 d] swz
    __shared__ __align__(16) u16 Vs[2 * 8192];   // 32 KB dbuf [64 d][128 t] swz

    // Q fragments in registers, pre-scaled by 0.125*log2(e) (log2-domain S)
    const u16* Qr = Q + ((size_t)(b * T_ + qb * 128 + wave * 16 + l16)) * D_ + h * HD_;
    bf16x8 qf[2];
    {
        const float qscale = 0.125f * 1.44269504f;
        union { u16 t[8]; bf16x8 v; } a, c;
#pragma unroll
        for (int ks = 0; ks < 2; ks++) {
            a.v = *(const bf16x8*)(Qr + ks * 32 + quad * 8);
#pragma unroll
            for (int j = 0; j < 8; j++) c.t[j] = f2bf(bf2f(a.t[j]) * qscale);
            qf[ks] = c.v;
        }
    }

    // ones B fragment for l-accum (16x16x16): B[k][0]=1 -> lanes l16==0 hold 1
    s16x4 ones4;
    {
        union { u16 t[4]; s16x4 v; } o;
        const u16 one = (l16 == 0) ? (u16)0x3F80 : (u16)0;
#pragma unroll
        for (int j = 0; j < 4; j++) o.t[j] = one;
        ones4 = o.v;
    }

    const u16* Kbase = K + ((size_t)(b * T_)) * D_ + h * HD_;
    const u16* Vbase = Vt + ((size_t)(b * H_ + h)) * HD_ * T_;

    f32x4 o_acc[4], o_l;
#pragma unroll
    for (int i = 0; i < 4; i++) o_acc[i] = (f32x4){0.f, 0.f, 0.f, 0.f};
    o_l = (f32x4){0.f, 0.f, 0.f, 0.f};
    float m_i = NEG_BIG;

    // loop-invariant per-lane LDS byte bases
    const int kb0b = (l16 * 64 + 8 * (quad ^ z3)) * 2;
    const int kb1b = (l16 * 64 + 8 * ((quad | 4) ^ z3)) * 2;
    int vbb[8];
#pragma unroll
    for (int ni = 0; ni < 8; ni++)
        vbb[ni] = (l16 * 128 + ((ni * 16 + quad * 4) ^ (z3 << 3))) * 2;

    const int nkb = qb + 1;

#define STAGE(KB, BSEL)                                                        \
    {                                                                          \
        const u16* Kg = Kbase + (size_t)(KB) * 128 * D_;                       \
        const u16* Vg = Vbase + (size_t)(KB) * 128;                            \
        u16* Kd = &Ks[(BSEL) * 8192];                                          \
        u16* Vd = &Vs[(BSEL) * 8192];                                          \
        _Pragma("unroll")                                                      \
        for (int i_ = 0; i_ < 2; i_++) {                                       \
            int idx = i_ * 512 + tid;                                          \
            int kr = idx >> 3, kblk = idx & 7;                                 \
            async_copy16(Kg + (size_t)kr * D_ + ((kblk ^ (kr & 7)) * 8),       \
                         Kd + idx * 8);                                        \
            int dv = idx >> 4, sv = idx & 15;                                  \
            async_copy16(Vg + (size_t)dv * T_ + 8 * (sv ^ (dv & 7)),           \
                         Vd + idx * 8);                                        \
        }                                                                      \
    }

#define TILE(CUR)                                                              \
    {                                                                          \
        if (kb + 1 < nkb) STAGE(kb + 1, (CUR) ^ 1);                            \
        const int nLim = (kb == nkb - 1) ? (wave + 1) : 8;                     \
        f32x4 s[8];                                                            \
        _Pragma("unroll")                                                      \
        for (int ni = 0; ni < 8; ni++) s[ni] = (f32x4){0.f, 0.f, 0.f, 0.f};    \
        __builtin_amdgcn_s_setprio(1);                                         \
        _Pragma("unroll")                                                      \
        for (int ni = 0; ni < 8; ni++)                                         \
            if (ni < nLim) {                                                   \
                bf16x8 b0 = *(const bf16x8*)((const char*)Ks                   \
                    + (CUR) * 16384 + ni * 2048 + kb0b);                       \
                s[ni] = __builtin_amdgcn_mfma_f32_16x16x32_bf16(               \
                    b0, qf[0], s[ni], 0, 0, 0);                                \
                bf16x8 b1 = *(const bf16x8*)((const char*)Ks                   \
                    + (CUR) * 16384 + ni * 2048 + kb1b);                       \
                s[ni] = __builtin_amdgcn_mfma_f32_16x16x32_bf16(               \
                    b1, qf[1], s[ni], 0, 0, 0);                                \
            }                                                                  \
        __builtin_amdgcn_s_setprio(0);                                         \
        if (kb == nkb - 1) {                                                   \
            const int qrow = qb * 128 + wave * 16 + l16;                       \
            const int kc0 = kb * 128 + quad * 4;                               \
            _Pragma("unroll")                                                  \
            for (int ni = 0; ni < 8; ni++)                                     \
                if (ni < nLim)                                                 \
                    _Pragma("unroll")                                          \
                    for (int r = 0; r < 4; r++)                                \
                        s[ni][r] = (kc0 + ni * 16 + r <= qrow)                 \
                                   ? s[ni][r] : NEG_BIG;                       \
        }                                                                      \
        float m8[8];                                                           \
        _Pragma("unroll")                                                      \
        for (int ni = 0; ni < 8; ni++)                                         \
            m8[ni] = (ni < nLim)                                               \
                ? fmaxf(fmaxf(fmaxf(s[ni][0], s[ni][1]), s[ni][2]), s[ni][3])  \
                : NEG_BIG;                                                     \
        float mnew = fmaxf(                                                    \
            fmaxf(fmaxf(fmaxf(m8[0], m8[1]), m8[2]), m8[3]),                   \
            fmaxf(fmaxf(fmaxf(m8[4], m8[5]), m8[6]), m8[7]));                  \
        mnew = fmaxf(mnew, __shfl_xor(mnew, 16, 64));                          \
        mnew = fmaxf(mnew, __shfl_xor(mnew, 32, 64));                          \
        if (!__all(mnew <= m_i)) {                                             \
            float mo = m_i;                                                    \
            m_i = fmaxf(m_i, mnew);                                            \
            float alpha = __builtin_amdgcn_exp2f(mo - m_i);                    \
            const int asrc = quad * 20;                                        \
            float a_o[4];                                                      \
            _Pragma("unroll")                                                  \
            for (int r = 0; r < 4; r++) a_o[r] = __shfl(alpha, asrc + r, 64);  \
            _Pragma("unroll")                                                  \
            for (int i = 0; i < 4; i++)                                        \
                _Pragma("unroll")                                              \
                for (int r = 0; r < 4; r++) o_acc[i][r] *= a_o[r];             \
            _Pragma("unroll")                                                  \
            for (int r = 0; r < 4; r++) o_l[r] *= a_o[r];                      \
        }                                                                      \
        s16x4 pa[8];                                                           \
        _Pragma("unroll")                                                      \
        for (int ni = 0; ni < 8; ni++)                                         \
            if (ni < nLim) {                                                   \
                union { u16 t[4]; s16x4 v; } c;                                \
                _Pragma("unroll")                                              \
                for (int r = 0; r < 4; r++) {                                  \
                    float p = __builtin_amdgcn_exp2f(s[ni][r] - m_i);          \
                    union { __bf16 b; u16 u; } cv;                             \
                    cv.b = (__bf16)p;                                          \
                    c.t[r] = cv.u;                                             \
                }                                                              \
                pa[ni] = c.v;                                                  \
            }                                                                  \
        __builtin_amdgcn_s_setprio(1);                                         \
        _Pragma("unroll")                                                      \
        for (int ni = 0; ni < 8; ni++)                                         \
            if (ni < nLim) {                                                   \
                _Pragma("unroll")                                              \
                for (int d0i = 0; d0i < 4; d0i++) {                            \
                    s16x4 vb = *(const s16x4*)((const char*)Vs                 \
                        + (CUR) * 16384 + d0i * 4096 + vbb[ni]);               \
                    o_acc[d0i] = __builtin_amdgcn_mfma_f32_16x16x16bf16_1k(    \
                        pa[ni], vb, o_acc[d0i], 0, 0, 0);                      \
                }                                                              \
                o_l = __builtin_amdgcn_mfma_f32_16x16x16bf16_1k(               \
                    pa[ni], ones4, o_l, 0, 0, 0);                              \
            }                                                                  \
        __builtin_amdgcn_s_setprio(0);                                         \
        __syncthreads();                                                       \
    }

    STAGE(0, 0);
    __syncthreads();   // drain prologue stage (vmcnt0 + barrier)

    int kb = 0;
    while (true) {
        TILE(0);
        if (++kb == nkb) break;
        TILE(1);
        if (++kb == nkb) break;
    }

    // l for output row quad*4+r sits at lane (same quad, l16=0), reg r
    float inv_o[4];
#pragma unroll
    for (int r = 0; r < 4; r++) {
        float lv = __shfl(o_l[r], lane & 48, 64);
        inv_o[r] = 1.f / fmaxf(lv, 1e-30f);
    }

    u16* Og = O + ((size_t)(b * T_ + qb * 128)) * D_ + h * HD_;
#pragma unroll
    for (int d0i = 0; d0i < 4; d0i++)
#pragma unroll
        for (int r = 0; r < 4; r++)
            Og[(size_t)(wave * 16 + quad * 4 + r) * D_ + d0i * 16 + l16] =
                f2bf(o_acc[d0i][r] * inv_o[r]);
#undef TILE
#undef STAGE
}

// ---------------------------------------------------------------------------
// Workspace (u16 elements), 32M used (64 MiB):
//   ws [0,  8M): Qbuf; attn O aliases it (per-(row,col) read-then-write)
//   ws [8, 16M): Kbuf; after attn -> WtO at [8M, 9M)
//   ws [16,24M): Vbuf
//   ws [24,27M): WtQKV (dead after QKV gemm) -> Vtbuf [24M, 32M)
//   d_out:       first 16 MB = xb (bf16 x) until QKV gemm; then fp32 output
// ---------------------------------------------------------------------------
extern "C" void kernel_launch(void* const* d_in, const int* in_sizes, int n_in,
                              void* d_out, int out_size, void* d_ws, size_t ws_size,
                              hipStream_t stream)
{
    (void)in_sizes; (void)n_in; (void)out_size; (void)ws_size;
    const float* x    = (const float*)d_in[0];
    const float* cosb = (const float*)d_in[2];
    const float* sinb = (const float*)d_in[3];
    const float* Wq   = (const float*)d_in[4];
    const float* bq   = (const float*)d_in[5];
    const float* Wk   = (const float*)d_in[6];
    const float* bk   = (const float*)d_in[7];
    const float* Wv   = (const float*)d_in[8];
    const float* bv   = (const float*)d_in[9];
    const float* Wo   = (const float*)d_in[10];
    const float* bo   = (const float*)d_in[11];

    u16* ws = (u16*)d_ws;
    const size_t MD = (size_t)M_ * D_;
    u16* xb     = (u16*)d_out;
    u16* Qbuf   = ws;
    u16* Kbuf   = ws + MD;
    u16* Vbuf   = ws + 2 * MD;
    u16* WtQKV  = ws + 3 * MD;
    u16* Vtbuf  = ws + 3 * MD;
    u16* WtO    = ws + MD;
    u16* Abuf   = ws;

    convert_x<<<dim3(M_ * D_ / 2048), 256, 0, stream>>>(x, xb);
    transpose_w<<<dim3(16, 16, 3), 256, 0, stream>>>(Wq, Wk, Wv, WtQKV);
    gemm_bt<0><<<dim3(64, 8, 3), 256, 0, stream>>>(xb, WtQKV, bq, bk, bv,
                                                   Qbuf, M_, D_, D_);
    rope_qk<<<dim3((B_ * T_ * H_ * 4) / 256), 256, 0, stream>>>(
        Qbuf, Kbuf, cosb, sinb);
    transpose_v<<<dim3(32, 16, 4), 256, 0, stream>>>(Vbuf, Vtbuf);
    attn_kernel<<<dim3(1024), 512, 0, stream>>>(Qbuf, Kbuf, Vtbuf, Abuf);
    transpose_w<<<dim3(16, 16, 1), 256, 0, stream>>>(Wo, Wo, Wo, WtO);
    gemm_bt<1><<<dim3(64, 8, 1), 256, 0, stream>>>(Abuf, WtO, bo, bo, bo,
                                                   d_out, M_, D_, D_);
}

// Round 8
// 313.182 us; speedup vs baseline: 1.1179x; 1.1179x over previous
//
#include <hip/hip_runtime.h>
#include <math.h>

typedef unsigned short u16;
typedef unsigned int   u32;
typedef __bf16  bf16x8 __attribute__((ext_vector_type(8)));
typedef short   s16x4  __attribute__((ext_vector_type(4)));
typedef float   f32x4  __attribute__((ext_vector_type(4)));

#define B_  4
#define T_  2048
#define D_  1024
#define H_  16
#define HD_ 64
#define M_  (B_*T_)   // 8192
#define NEG_BIG (-30000.0f)

__device__ __forceinline__ float bf2f(u16 h) {
    u32 u = ((u32)h) << 16;
    return __uint_as_float(u);
}
__device__ __forceinline__ u16 f2bf(float f) {
    u32 u = __float_as_uint(f);
    u32 r = (u + 0x7fffu + ((u >> 16) & 1u)) >> 16;
    return (u16)r;
}
__device__ __forceinline__ void async_copy16(const u16* g, u16* l) {
    __builtin_amdgcn_global_load_lds(
        (const __attribute__((address_space(1))) u32*)g,
        (__attribute__((address_space(3))) u32*)l, 16, 0, 0);
}

// ---------------------------------------------------------------------------
// x (fp32) -> bf16, vectorized. 8 elements/thread.
// ---------------------------------------------------------------------------
__global__ __launch_bounds__(256)
void convert_x(const float* __restrict__ X, u16* __restrict__ Xb)
{
    const int id = (blockIdx.x * 256 + threadIdx.x) * 8;
    float4 f0 = *(const float4*)(X + id);
    float4 f1 = *(const float4*)(X + id + 4);
    union { u16 t[8]; uint4 v; } c;
    c.t[0] = f2bf(f0.x); c.t[1] = f2bf(f0.y); c.t[2] = f2bf(f0.z); c.t[3] = f2bf(f0.w);
    c.t[4] = f2bf(f1.x); c.t[5] = f2bf(f1.y); c.t[6] = f2bf(f1.z); c.t[7] = f2bf(f1.w);
    *(uint4*)(Xb + id) = c.v;
}

// ---------------------------------------------------------------------------
// bf16 MFMA GEMM, B^T layout, v12: BK=64 with 8-elem-block XOR swizzle
// (same verified pattern as attn v10's K staging). Barriers per K halved
// vs BK=32; 128B-stride LDS reads stay 2-way-free via the swizzle.
// LDS 32 KB (As+Bs) -> occupancy still reg-limited (~3 blocks/CU).
// ---------------------------------------------------------------------------
template<int OUT_F32>
__global__ __launch_bounds__(256)
void gemm_bt(const u16* __restrict__ A, const u16* __restrict__ Bt_base,
             const float* __restrict__ bias0, const float* __restrict__ bias1,
             const float* __restrict__ bias2,
             void* __restrict__ C_base, int M, int N, int K)
{
    const int z = blockIdx.z;
    const u16* Bt  = Bt_base + (size_t)z * N * K;
    const float* bias = (z == 0) ? bias0 : ((z == 1) ? bias1 : bias2);

    const int m0 = blockIdx.x * 128, n0 = blockIdx.y * 128;
    const int tid = threadIdx.x, lane = tid & 63, wave = tid >> 6;
    const int wm = (wave >> 1) * 64, wn = (wave & 1) * 64;
    const int quad = lane >> 4, l16 = lane & 15;
    const int z3 = l16 & 7;

    __shared__ __align__(16) u16 As[128 * 64];   // 16 KB, row-major swz blocks
    __shared__ __align__(16) u16 Bs[128 * 64];   // 16 KB

    // per-lane read col offsets (elems): block (ks*4+quad) ^ z3
    const int c0 = 8 * (quad ^ z3);
    const int c1 = 8 * ((quad | 4) ^ z3);

    f32x4 acc[4][4];
#pragma unroll
    for (int i = 0; i < 4; i++)
#pragma unroll
        for (int j = 0; j < 4; j++) acc[i][j] = (f32x4){0.f, 0.f, 0.f, 0.f};

    for (int k0 = 0; k0 < K; k0 += 64) {
        __syncthreads();
#pragma unroll
        for (int i = 0; i < 4; i++) {
            int idx = i * 256 + tid;           // 0..1023: r=idx>>3, blk=idx&7
            int r = idx >> 3;
            int sc = 8 * ((idx & 7) ^ (r & 7));   // pre-swizzled source col
            async_copy16(A  + (size_t)(m0 + r) * K + k0 + sc, &As[idx * 8]);
            async_copy16(Bt + (size_t)(n0 + r) * K + k0 + sc, &Bs[idx * 8]);
        }
        __syncthreads();

#pragma unroll
        for (int ks = 0; ks < 2; ks++) {
            const int cc = ks ? c1 : c0;
            bf16x8 af[4], bfr[4];
#pragma unroll
            for (int mi = 0; mi < 4; mi++)
                af[mi] = *(const bf16x8*)&As[(wm + mi * 16 + l16) * 64 + cc];
#pragma unroll
            for (int ni = 0; ni < 4; ni++)
                bfr[ni] = *(const bf16x8*)&Bs[(wn + ni * 16 + l16) * 64 + cc];
#pragma unroll
            for (int mi = 0; mi < 4; mi++)
#pragma unroll
                for (int ni = 0; ni < 4; ni++)
                    acc[mi][ni] = __builtin_amdgcn_mfma_f32_16x16x32_bf16(
                        af[mi], bfr[ni], acc[mi][ni], 0, 0, 0);
        }
    }

    float bv[4];
#pragma unroll
    for (int ni = 0; ni < 4; ni++) bv[ni] = bias[n0 + wn + ni * 16 + l16];
#pragma unroll
    for (int mi = 0; mi < 4; mi++) {
#pragma unroll
        for (int reg = 0; reg < 4; reg++) {
            int row = m0 + wm + mi * 16 + quad * 4 + reg;
#pragma unroll
            for (int ni = 0; ni < 4; ni++) {
                int col = n0 + wn + ni * 16 + l16;
                float v = acc[mi][ni][reg] + bv[ni];
                if (OUT_F32)
                    ((float*)C_base + (size_t)z * M * N)[(size_t)row * N + col] = v;
                else
                    ((u16*)C_base + (size_t)z * M * N)[(size_t)row * N + col] = f2bf(v);
            }
        }
    }
}

// ---------------------------------------------------------------------------
// Transpose + convert fp32 weight (D x D) -> bf16 Wt[n][k] = W[k][n].
// ---------------------------------------------------------------------------
__global__ __launch_bounds__(256)
void transpose_w(const float* __restrict__ w0, const float* __restrict__ w1,
                 const float* __restrict__ w2,
                 u16* __restrict__ out)
{
    const int z = blockIdx.z;
    const float* W = (z == 0) ? w0 : ((z == 1) ? w1 : w2);
    u16* Wt = out + (size_t)z * D_ * D_;
    const int k0 = blockIdx.x * 64, n0 = blockIdx.y * 64;
    __shared__ u16 tl[64][72];
    const int tid = threadIdx.x;
    const int r = tid >> 2, c4 = (tid & 3) * 16;
#pragma unroll
    for (int j = 0; j < 4; j++) {
        float4 fv = *(const float4*)(W + (size_t)(k0 + r) * D_ + n0 + c4 + j * 4);
        tl[r][c4 + j * 4 + 0] = f2bf(fv.x);
        tl[r][c4 + j * 4 + 1] = f2bf(fv.y);
        tl[r][c4 + j * 4 + 2] = f2bf(fv.z);
        tl[r][c4 + j * 4 + 3] = f2bf(fv.w);
    }
    __syncthreads();
    u16 vals[16];
#pragma unroll
    for (int j = 0; j < 16; j++) vals[j] = tl[c4 + j][r];
#pragma unroll
    for (int j = 0; j < 2; j++)
        *(uint4*)(Wt + (size_t)(n0 + r) * D_ + k0 + c4 + j * 8) =
            *(const uint4*)&vals[j * 8];
}

// ---------------------------------------------------------------------------
// Transpose V (B,T,H,HD) bf16 -> Vt (B,H,HD,T) bf16
// ---------------------------------------------------------------------------
__global__ __launch_bounds__(256)
void transpose_v(const u16* __restrict__ V, u16* __restrict__ Vt)
{
    const int t0 = blockIdx.x * 64;
    const int h = blockIdx.y, b = blockIdx.z;
    __shared__ u16 tl[64][72];
    const int tid = threadIdx.x;
    const int r = tid >> 2, c4 = (tid & 3) * 16;
    const u16* Vg = V + ((size_t)(b * T_ + t0)) * D_ + h * HD_;
#pragma unroll
    for (int j = 0; j < 2; j++)
        *(uint4*)&tl[r][c4 + j * 8] =
            *(const uint4*)(Vg + (size_t)r * D_ + c4 + j * 8);
    __syncthreads();
    u16 vals[16];
#pragma unroll
    for (int j = 0; j < 16; j++) vals[j] = tl[c4 + j][r];
    u16* Og = Vt + ((size_t)(b * H_ + h)) * HD_ * T_ + (size_t)r * T_ + t0 + c4;
#pragma unroll
    for (int j = 0; j < 2; j++)
        *(uint4*)(Og + j * 8) = *(const uint4*)&vals[j * 8];
}

// ---------------------------------------------------------------------------
// RoPE on Q and K in place (bf16), vectorized (G13).
// ---------------------------------------------------------------------------
__global__ __launch_bounds__(256)
void rope_qk(u16* __restrict__ Q, u16* __restrict__ K,
             const float* __restrict__ cosb, const float* __restrict__ sinb)
{
    int g  = blockIdx.x * 256 + threadIdx.x;     // B*T*H*4 threads total
    int d0 = (g & 3) * 8;
    int h  = (g >> 2) & (H_ - 1);
    int bt = g >> 6;
    int t  = bt & (T_ - 1);
    size_t off = (size_t)bt * D_ + h * HD_ + d0;

    const float* cp = cosb + (size_t)t * HD_ + d0;
    const float* sp = sinb + (size_t)t * HD_ + d0;
    float4 c1a = *(const float4*)(cp);
    float4 c1b = *(const float4*)(cp + 4);
    float4 s1a = *(const float4*)(sp);
    float4 s1b = *(const float4*)(sp + 4);
    float4 c2a = *(const float4*)(cp + 32);
    float4 c2b = *(const float4*)(cp + 36);
    float4 s2a = *(const float4*)(sp + 32);
    float4 s2b = *(const float4*)(sp + 36);
    float c1[8] = {c1a.x,c1a.y,c1a.z,c1a.w,c1b.x,c1b.y,c1b.z,c1b.w};
    float s1[8] = {s1a.x,s1a.y,s1a.z,s1a.w,s1b.x,s1b.y,s1b.z,s1b.w};
    float c2[8] = {c2a.x,c2a.y,c2a.z,c2a.w,c2b.x,c2b.y,c2b.z,c2b.w};
    float s2[8] = {s2a.x,s2a.y,s2a.z,s2a.w,s2b.x,s2b.y,s2b.z,s2b.w};

    {
        union { u16 t[8]; uint4 v; } x1, x2, o1, o2;
        x1.v = *(const uint4*)(Q + off);
        x2.v = *(const uint4*)(Q + off + 32);
#pragma unroll
        for (int j = 0; j < 8; j++) {
            float a = bf2f(x1.t[j]), b = bf2f(x2.t[j]);
            o1.t[j] = f2bf(a * c1[j] - b * s1[j]);
            o2.t[j] = f2bf(b * c2[j] + a * s2[j]);
        }
        *(uint4*)(Q + off)      = o1.v;
        *(uint4*)(Q + off + 32) = o2.v;
    }
    {
        union { u16 t[8]; uint4 v; } x1, x2, o1, o2;
        x1.v = *(const uint4*)(K + off);
        x2.v = *(const uint4*)(K + off + 32);
#pragma unroll
        for (int j = 0; j < 8; j++) {
            float a = bf2f(x1.t[j]), b = bf2f(x2.t[j]);
            o1.t[j] = f2bf(a * c1[j] - b * s1[j]);
            o2.t[j] = f2bf(b * c2[j] + a * s2[j]);
        }
        *(uint4*)(K + off)      = o1.v;
        *(uint4*)(K + off + 32) = o2.v;
    }
}

// ---------------------------------------------------------------------------
// Causal MFMA flash attention, v10 VERBATIM (93.7 us verified; v11's
// hoist/unroll/builtin bundle regressed to 124.6 us via VGPR 64->124 and
// occupancy 37->22% -- reverted wholesale).
// ---------------------------------------------------------------------------
__global__ __launch_bounds__(512, 2)
void attn_kernel(const u16* __restrict__ Q, const u16* __restrict__ K,
                 const u16* __restrict__ Vt, u16* __restrict__ O)
{
    const int id = blockIdx.x;
    const int xcd = id & 7, rr = id >> 3;   // rr in 0..127
    const int qb = 15 - (rr >> 3);          // monotone heavy -> light per XCD
    const int hb = xcd + 8 * (rr & 7);      // (b,h) pinned to one XCD
    const int h = hb & 15, b = hb >> 4;
    const int tid = threadIdx.x, lane = tid & 63, wave = tid >> 6;
    const int quad = lane >> 4, l16 = lane & 15;
    const int z3 = l16 & 7;

    __shared__ __align__(16) u16 Ks[2 * 8192];   // 32 KB dbuf [128 row][64 d] swz
    __shared__ __align__(16) u16 Vs[2 * 8192];   // 32 KB dbuf [64 d][128 t] swz

    // Q fragments in registers, pre-scaled by 0.125*log2(e) (log2-domain S)
    const u16* Qr = Q + ((size_t)(b * T_ + qb * 128 + wave * 16 + l16)) * D_ + h * HD_;
    bf16x8 qf[2];
    {
        const float qscale = 0.125f * 1.44269504f;
        union { u16 t[8]; bf16x8 v; } a, c;
#pragma unroll
        for (int ks = 0; ks < 2; ks++) {
            a.v = *(const bf16x8*)(Qr + ks * 32 + quad * 8);
#pragma unroll
            for (int j = 0; j < 8; j++) c.t[j] = f2bf(bf2f(a.t[j]) * qscale);
            qf[ks] = c.v;
        }
    }

    // ones B fragment for l-accum (16x16x16): B[k][0]=1 -> lanes l16==0 hold 1
    s16x4 ones4;
    {
        union { u16 t[4]; s16x4 v; } o;
        const u16 one = (l16 == 0) ? (u16)0x3F80 : (u16)0;
#pragma unroll
        for (int j = 0; j < 4; j++) o.t[j] = one;
        ones4 = o.v;
    }

    const u16* Kbase = K + ((size_t)(b * T_)) * D_ + h * HD_;
    const u16* Vbase = Vt + ((size_t)(b * H_ + h)) * HD_ * T_;

    f32x4 o_acc[4], o_l;
#pragma unroll
    for (int i = 0; i < 4; i++) o_acc[i] = (f32x4){0.f, 0.f, 0.f, 0.f};
    o_l = (f32x4){0.f, 0.f, 0.f, 0.f};
    float m_i = NEG_BIG;

    // per-lane K read bases (swizzled layout): row = ni*16+l16, block = (ks*4+quad)^z3
    const int kb0 = l16 * 64 + 8 * (quad ^ z3);
    const int kb1 = l16 * 64 + 8 * ((quad | 4) ^ z3);
    const int vsw = z3 << 3, vq = quad * 4;

    const int nkb = qb + 1;

#define STAGE(KB, BSEL)                                                        \
    {                                                                          \
        const u16* Kg = Kbase + (size_t)(KB) * 128 * D_;                       \
        const u16* Vg = Vbase + (size_t)(KB) * 128;                            \
        u16* Kd = &Ks[(BSEL) * 8192];                                          \
        u16* Vd = &Vs[(BSEL) * 8192];                                          \
        _Pragma("unroll")                                                      \
        for (int i_ = 0; i_ < 2; i_++) {                                       \
            int idx = i_ * 512 + tid;                                          \
            /* K: row = idx>>3, blk = idx&7; src blk pre-swizzled */           \
            int kr = idx >> 3, kblk = idx & 7;                                 \
            async_copy16(Kg + (size_t)kr * D_ + ((kblk ^ (kr & 7)) * 8),       \
                         Kd + idx * 8);                                        \
            /* V: d-row = idx>>4, 8-elem src block pre-swizzled */             \
            int dv = idx >> 4, sv = idx & 15;                                  \
            async_copy16(Vg + (size_t)dv * T_ + 8 * (sv ^ (dv & 7)),           \
                         Vd + idx * 8);                                        \
        }                                                                      \
    }

    STAGE(0, 0);
    __syncthreads();   // drain prologue stage (vmcnt0 + barrier)

    int cur = 0;
    for (int kb = 0; kb < nkb; kb++) {
        if (kb + 1 < nkb) STAGE(kb + 1, cur ^ 1);   // prefetch overlaps compute

        const u16* Kc = &Ks[cur * 8192];
        const u16* Vc = &Vs[cur * 8192];

        // diagonal tile: wave covers qrows wave*16+[0,16) -> ni <= wave
        const int nLim = (kb == nkb - 1) ? (wave + 1) : 8;

        // S^T = K (Q*c)^T : lane holds q-row = l16, k-col = ni*16+quad*4+r
        f32x4 s[8];
#pragma unroll
        for (int ni = 0; ni < 8; ni++) s[ni] = (f32x4){0.f, 0.f, 0.f, 0.f};
        __builtin_amdgcn_s_setprio(1);
#pragma unroll
        for (int ni = 0; ni < 8; ni++)
            if (ni < nLim) {
                bf16x8 b0 = *(const bf16x8*)&Kc[kb0 + ni * 1024];
                s[ni] = __builtin_amdgcn_mfma_f32_16x16x32_bf16(b0, qf[0], s[ni], 0, 0, 0);
                bf16x8 b1 = *(const bf16x8*)&Kc[kb1 + ni * 1024];
                s[ni] = __builtin_amdgcn_mfma_f32_16x16x32_bf16(b1, qf[1], s[ni], 0, 0, 0);
            }
        __builtin_amdgcn_s_setprio(0);

        // diagonal masking (log2-domain values; comparisons unaffected)
        if (kb == nkb - 1) {
            const int qrow = qb * 128 + wave * 16 + l16;
            const int kc0 = kb * 128 + quad * 4;
#pragma unroll
            for (int ni = 0; ni < 8; ni++)
                if (ni < nLim)
#pragma unroll
                    for (int r = 0; r < 4; r++)
                        s[ni][r] = (kc0 + ni * 16 + r <= qrow) ? s[ni][r] : NEG_BIG;
        }

        // row max: per-ni max4, then tree over 8, then cross-quad
        float m8[8];
#pragma unroll
        for (int ni = 0; ni < 8; ni++)
            m8[ni] = (ni < nLim)
                ? fmaxf(fmaxf(s[ni][0], s[ni][1]), fmaxf(s[ni][2], s[ni][3]))
                : NEG_BIG;
        float mnew = fmaxf(fmaxf(fmaxf(m8[0], m8[1]), fmaxf(m8[2], m8[3])),
                           fmaxf(fmaxf(m8[4], m8[5]), fmaxf(m8[6], m8[7])));
        mnew = fmaxf(mnew, __shfl_xor(mnew, 16, 64));
        mnew = fmaxf(mnew, __shfl_xor(mnew, 32, 64));

        // defer-max: skip rescale entirely when no row's max grew (exact, THR=0)
        if (!__all(mnew <= m_i)) {
            float mo = m_i;
            m_i = fmaxf(m_i, mnew);
            float alpha = exp2f(mo - m_i);
            const int asrc = quad * 20;   // lane l16 = quad*4+r within quad
            float a_o[4];
#pragma unroll
            for (int r = 0; r < 4; r++) a_o[r] = __shfl(alpha, asrc + r, 64);
#pragma unroll
            for (int i = 0; i < 4; i++)
#pragma unroll
                for (int r = 0; r < 4; r++) o_acc[i][r] *= a_o[r];
#pragma unroll
            for (int r = 0; r < 4; r++) o_l[r] *= a_o[r];
        }

        // P = exp2(S - m) packed to 16x16x16 A-fragments
        s16x4 pa[8];
#pragma unroll
        for (int ni = 0; ni < 8; ni++)
            if (ni < nLim) {
                union { u16 t[4]; s16x4 v; } c;
#pragma unroll
                for (int r = 0; r < 4; r++) {
                    float p = exp2f(s[ni][r] - m_i);
                    union { __bf16 b; u16 u; } cv;
                    cv.b = (__bf16)p;
                    c.t[r] = cv.u;
                }
                pa[ni] = c.v;
            }

        // O += P V ; l += P * ones  (16x16x16 MFMA; V b64 from swizzled Vs)
        __builtin_amdgcn_s_setprio(1);
#pragma unroll
        for (int ni = 0; ni < 8; ni++)
            if (ni < nLim) {
#pragma unroll
                for (int d0i = 0; d0i < 4; d0i++) {
                    int uidx = (d0i * 16 + l16) * 128 + ((ni * 16 + vq) ^ vsw);
                    s16x4 vb = *(const s16x4*)&Vc[uidx];
                    o_acc[d0i] = __builtin_amdgcn_mfma_f32_16x16x16bf16_1k(
                        pa[ni], vb, o_acc[d0i], 0, 0, 0);
                }
                o_l = __builtin_amdgcn_mfma_f32_16x16x16bf16_1k(
                    pa[ni], ones4, o_l, 0, 0, 0);
            }
        __builtin_amdgcn_s_setprio(0);

        __syncthreads();   // reads of buf done + next stage drained
        cur ^= 1;
    }

    // l for output row quad*4+r sits at lane (same quad, l16=0), reg r
    float inv_o[4];
#pragma unroll
    for (int r = 0; r < 4; r++) {
        float lv = __shfl(o_l[r], lane & 48, 64);
        inv_o[r] = 1.f / fmaxf(lv, 1e-30f);
    }

    u16* Og = O + ((size_t)(b * T_ + qb * 128)) * D_ + h * HD_;
#pragma unroll
    for (int d0i = 0; d0i < 4; d0i++)
#pragma unroll
        for (int r = 0; r < 4; r++)
            Og[(size_t)(wave * 16 + quad * 4 + r) * D_ + d0i * 16 + l16] =
                f2bf(o_acc[d0i][r] * inv_o[r]);
#undef STAGE
}

// ---------------------------------------------------------------------------
// Workspace (u16 elements), 32M used (64 MiB):
//   ws [0,  8M): Qbuf; attn O aliases it (per-(row,col) read-then-write)
//   ws [8, 16M): Kbuf; after attn -> WtO at [8M, 9M)
//   ws [16,24M): Vbuf
//   ws [24,27M): WtQKV (dead after QKV gemm) -> Vtbuf [24M, 32M)
//   d_out:       first 16 MB = xb (bf16 x) until QKV gemm; then fp32 output
// ---------------------------------------------------------------------------
extern "C" void kernel_launch(void* const* d_in, const int* in_sizes, int n_in,
                              void* d_out, int out_size, void* d_ws, size_t ws_size,
                              hipStream_t stream)
{
    (void)in_sizes; (void)n_in; (void)out_size; (void)ws_size;
    const float* x    = (const float*)d_in[0];
    const float* cosb = (const float*)d_in[2];
    const float* sinb = (const float*)d_in[3];
    const float* Wq   = (const float*)d_in[4];
    const float* bq   = (const float*)d_in[5];
    const float* Wk   = (const float*)d_in[6];
    const float* bk   = (const float*)d_in[7];
    const float* Wv   = (const float*)d_in[8];
    const float* bv   = (const float*)d_in[9];
    const float* Wo   = (const float*)d_in[10];
    const float* bo   = (const float*)d_in[11];

    u16* ws = (u16*)d_ws;
    const size_t MD = (size_t)M_ * D_;
    u16* xb     = (u16*)d_out;
    u16* Qbuf   = ws;
    u16* Kbuf   = ws + MD;
    u16* Vbuf   = ws + 2 * MD;
    u16* WtQKV  = ws + 3 * MD;
    u16* Vtbuf  = ws + 3 * MD;
    u16* WtO    = ws + MD;
    u16* Abuf   = ws;

    convert_x<<<dim3(M_ * D_ / 2048), 256, 0, stream>>>(x, xb);
    transpose_w<<<dim3(16, 16, 3), 256, 0, stream>>>(Wq, Wk, Wv, WtQKV);
    gemm_bt<0><<<dim3(64, 8, 3), 256, 0, stream>>>(xb, WtQKV, bq, bk, bv,
                                                   Qbuf, M_, D_, D_);
    rope_qk<<<dim3((B_ * T_ * H_ * 4) / 256), 256, 0, stream>>>(
        Qbuf, Kbuf, cosb, sinb);
    transpose_v<<<dim3(32, 16, 4), 256, 0, stream>>>(Vbuf, Vtbuf);
    attn_kernel<<<dim3(1024), 512, 0, stream>>>(Qbuf, Kbuf, Vtbuf, Abuf);
    transpose_w<<<dim3(16, 16, 1), 256, 0, stream>>>(Wo, Wo, Wo, WtO);
    gemm_bt<1><<<dim3(64, 8, 1), 256, 0, stream>>>(Abuf, WtO, bo, bo, bo,
                                                   d_out, M_, D_, D_);
}

// Round 10
// 286.928 us; speedup vs baseline: 1.2202x; 1.0915x over previous
//
#include <hip/hip_runtime.h>
#include <math.h>

typedef unsigned short u16;
typedef unsigned int   u32;
typedef __bf16  bf16x8 __attribute__((ext_vector_type(8)));
typedef short   s16x4  __attribute__((ext_vector_type(4)));
typedef float   f32x4  __attribute__((ext_vector_type(4)));

#define B_  4
#define T_  2048
#define D_  1024
#define H_  16
#define HD_ 64
#define M_  (B_*T_)   // 8192
#define NEG_BIG (-30000.0f)

__device__ __forceinline__ float bf2f(u16 h) {
    u32 u = ((u32)h) << 16;
    return __uint_as_float(u);
}
__device__ __forceinline__ u16 f2bf(float f) {
    u32 u = __float_as_uint(f);
    u32 r = (u + 0x7fffu + ((u >> 16) & 1u)) >> 16;
    return (u16)r;
}
__device__ __forceinline__ void async_copy16(const u16* g, u16* l) {
    __builtin_amdgcn_global_load_lds(
        (const __attribute__((address_space(1))) u32*)g,
        (__attribute__((address_space(3))) u32*)l, 16, 0, 0);
}

// ---------------------------------------------------------------------------
// x (fp32) -> bf16, vectorized. 8 elements/thread.
// ---------------------------------------------------------------------------
__global__ __launch_bounds__(256)
void convert_x(const float* __restrict__ X, u16* __restrict__ Xb)
{
    const int id = (blockIdx.x * 256 + threadIdx.x) * 8;
    float4 f0 = *(const float4*)(X + id);
    float4 f1 = *(const float4*)(X + id + 4);
    union { u16 t[8]; uint4 v; } c;
    c.t[0] = f2bf(f0.x); c.t[1] = f2bf(f0.y); c.t[2] = f2bf(f0.z); c.t[3] = f2bf(f0.w);
    c.t[4] = f2bf(f1.x); c.t[5] = f2bf(f1.y); c.t[6] = f2bf(f1.z); c.t[7] = f2bf(f1.w);
    *(uint4*)(Xb + id) = c.v;
}

// ---------------------------------------------------------------------------
// bf16 MFMA GEMM, B^T layout, v12: BK=64 with 8-elem-block XOR swizzle
// (kept from R8: 313.2 us total, mildly positive vs BK=32).
// ---------------------------------------------------------------------------
template<int OUT_F32>
__global__ __launch_bounds__(256)
void gemm_bt(const u16* __restrict__ A, const u16* __restrict__ Bt_base,
             const float* __restrict__ bias0, const float* __restrict__ bias1,
             const float* __restrict__ bias2,
             void* __restrict__ C_base, int M, int N, int K)
{
    const int z = blockIdx.z;
    const u16* Bt  = Bt_base + (size_t)z * N * K;
    const float* bias = (z == 0) ? bias0 : ((z == 1) ? bias1 : bias2);

    const int m0 = blockIdx.x * 128, n0 = blockIdx.y * 128;
    const int tid = threadIdx.x, lane = tid & 63, wave = tid >> 6;
    const int wm = (wave >> 1) * 64, wn = (wave & 1) * 64;
    const int quad = lane >> 4, l16 = lane & 15;
    const int z3 = l16 & 7;

    __shared__ __align__(16) u16 As[128 * 64];   // 16 KB, row-major swz blocks
    __shared__ __align__(16) u16 Bs[128 * 64];   // 16 KB

    // per-lane read col offsets (elems): block (ks*4+quad) ^ z3
    const int c0 = 8 * (quad ^ z3);
    const int c1 = 8 * ((quad | 4) ^ z3);

    f32x4 acc[4][4];
#pragma unroll
    for (int i = 0; i < 4; i++)
#pragma unroll
        for (int j = 0; j < 4; j++) acc[i][j] = (f32x4){0.f, 0.f, 0.f, 0.f};

    for (int k0 = 0; k0 < K; k0 += 64) {
        __syncthreads();
#pragma unroll
        for (int i = 0; i < 4; i++) {
            int idx = i * 256 + tid;           // 0..1023: r=idx>>3, blk=idx&7
            int r = idx >> 3;
            int sc = 8 * ((idx & 7) ^ (r & 7));   // pre-swizzled source col
            async_copy16(A  + (size_t)(m0 + r) * K + k0 + sc, &As[idx * 8]);
            async_copy16(Bt + (size_t)(n0 + r) * K + k0 + sc, &Bs[idx * 8]);
        }
        __syncthreads();

#pragma unroll
        for (int ks = 0; ks < 2; ks++) {
            const int cc = ks ? c1 : c0;
            bf16x8 af[4], bfr[4];
#pragma unroll
            for (int mi = 0; mi < 4; mi++)
                af[mi] = *(const bf16x8*)&As[(wm + mi * 16 + l16) * 64 + cc];
#pragma unroll
            for (int ni = 0; ni < 4; ni++)
                bfr[ni] = *(const bf16x8*)&Bs[(wn + ni * 16 + l16) * 64 + cc];
#pragma unroll
            for (int mi = 0; mi < 4; mi++)
#pragma unroll
                for (int ni = 0; ni < 4; ni++)
                    acc[mi][ni] = __builtin_amdgcn_mfma_f32_16x16x32_bf16(
                        af[mi], bfr[ni], acc[mi][ni], 0, 0, 0);
        }
    }

    float bv[4];
#pragma unroll
    for (int ni = 0; ni < 4; ni++) bv[ni] = bias[n0 + wn + ni * 16 + l16];
#pragma unroll
    for (int mi = 0; mi < 4; mi++) {
#pragma unroll
        for (int reg = 0; reg < 4; reg++) {
            int row = m0 + wm + mi * 16 + quad * 4 + reg;
#pragma unroll
            for (int ni = 0; ni < 4; ni++) {
                int col = n0 + wn + ni * 16 + l16;
                float v = acc[mi][ni][reg] + bv[ni];
                if (OUT_F32)
                    ((float*)C_base + (size_t)z * M * N)[(size_t)row * N + col] = v;
                else
                    ((u16*)C_base + (size_t)z * M * N)[(size_t)row * N + col] = f2bf(v);
            }
        }
    }
}

// ---------------------------------------------------------------------------
// Transpose + convert fp32 weight (D x D) -> bf16 Wt[n][k] = W[k][n].
// ---------------------------------------------------------------------------
__global__ __launch_bounds__(256)
void transpose_w(const float* __restrict__ w0, const float* __restrict__ w1,
                 const float* __restrict__ w2,
                 u16* __restrict__ out)
{
    const int z = blockIdx.z;
    const float* W = (z == 0) ? w0 : ((z == 1) ? w1 : w2);
    u16* Wt = out + (size_t)z * D_ * D_;
    const int k0 = blockIdx.x * 64, n0 = blockIdx.y * 64;
    __shared__ u16 tl[64][72];
    const int tid = threadIdx.x;
    const int r = tid >> 2, c4 = (tid & 3) * 16;
#pragma unroll
    for (int j = 0; j < 4; j++) {
        float4 fv = *(const float4*)(W + (size_t)(k0 + r) * D_ + n0 + c4 + j * 4);
        tl[r][c4 + j * 4 + 0] = f2bf(fv.x);
        tl[r][c4 + j * 4 + 1] = f2bf(fv.y);
        tl[r][c4 + j * 4 + 2] = f2bf(fv.z);
        tl[r][c4 + j * 4 + 3] = f2bf(fv.w);
    }
    __syncthreads();
    u16 vals[16];
#pragma unroll
    for (int j = 0; j < 16; j++) vals[j] = tl[c4 + j][r];
#pragma unroll
    for (int j = 0; j < 2; j++)
        *(uint4*)(Wt + (size_t)(n0 + r) * D_ + k0 + c4 + j * 8) =
            *(const uint4*)&vals[j * 8];
}

// ---------------------------------------------------------------------------
// Transpose V (B,T,H,HD) bf16 -> Vt (B,H,HD,T) bf16
// ---------------------------------------------------------------------------
__global__ __launch_bounds__(256)
void transpose_v(const u16* __restrict__ V, u16* __restrict__ Vt)
{
    const int t0 = blockIdx.x * 64;
    const int h = blockIdx.y, b = blockIdx.z;
    __shared__ u16 tl[64][72];
    const int tid = threadIdx.x;
    const int r = tid >> 2, c4 = (tid & 3) * 16;
    const u16* Vg = V + ((size_t)(b * T_ + t0)) * D_ + h * HD_;
#pragma unroll
    for (int j = 0; j < 2; j++)
        *(uint4*)&tl[r][c4 + j * 8] =
            *(const uint4*)(Vg + (size_t)r * D_ + c4 + j * 8);
    __syncthreads();
    u16 vals[16];
#pragma unroll
    for (int j = 0; j < 16; j++) vals[j] = tl[c4 + j][r];
    u16* Og = Vt + ((size_t)(b * H_ + h)) * HD_ * T_ + (size_t)r * T_ + t0 + c4;
#pragma unroll
    for (int j = 0; j < 2; j++)
        *(uint4*)(Og + j * 8) = *(const uint4*)&vals[j * 8];
}

// ---------------------------------------------------------------------------
// RoPE on Q and K in place (bf16), vectorized (G13).
// ---------------------------------------------------------------------------
__global__ __launch_bounds__(256)
void rope_qk(u16* __restrict__ Q, u16* __restrict__ K,
             const float* __restrict__ cosb, const float* __restrict__ sinb)
{
    int g  = blockIdx.x * 256 + threadIdx.x;     // B*T*H*4 threads total
    int d0 = (g & 3) * 8;
    int h  = (g >> 2) & (H_ - 1);
    int bt = g >> 6;
    int t  = bt & (T_ - 1);
    size_t off = (size_t)bt * D_ + h * HD_ + d0;

    const float* cp = cosb + (size_t)t * HD_ + d0;
    const float* sp = sinb + (size_t)t * HD_ + d0;
    float4 c1a = *(const float4*)(cp);
    float4 c1b = *(const float4*)(cp + 4);
    float4 s1a = *(const float4*)(sp);
    float4 s1b = *(const float4*)(sp + 4);
    float4 c2a = *(const float4*)(cp + 32);
    float4 c2b = *(const float4*)(cp + 36);
    float4 s2a = *(const float4*)(sp + 32);
    float4 s2b = *(const float4*)(sp + 36);
    float c1[8] = {c1a.x,c1a.y,c1a.z,c1a.w,c1b.x,c1b.y,c1b.z,c1b.w};
    float s1[8] = {s1a.x,s1a.y,s1a.z,s1a.w,s1b.x,s1b.y,s1b.z,s1b.w};
    float c2[8] = {c2a.x,c2a.y,c2a.z,c2a.w,c2b.x,c2b.y,c2b.z,c2b.w};
    float s2[8] = {s2a.x,s2a.y,s2a.z,s2a.w,s2b.x,s2b.y,s2b.z,s2b.w};

    {
        union { u16 t[8]; uint4 v; } x1, x2, o1, o2;
        x1.v = *(const uint4*)(Q + off);
        x2.v = *(const uint4*)(Q + off + 32);
#pragma unroll
        for (int j = 0; j < 8; j++) {
            float a = bf2f(x1.t[j]), b = bf2f(x2.t[j]);
            o1.t[j] = f2bf(a * c1[j] - b * s1[j]);
            o2.t[j] = f2bf(b * c2[j] + a * s2[j]);
        }
        *(uint4*)(Q + off)      = o1.v;
        *(uint4*)(Q + off + 32) = o2.v;
    }
    {
        union { u16 t[8]; uint4 v; } x1, x2, o1, o2;
        x1.v = *(const uint4*)(K + off);
        x2.v = *(const uint4*)(K + off + 32);
#pragma unroll
        for (int j = 0; j < 8; j++) {
            float a = bf2f(x1.t[j]), b = bf2f(x2.t[j]);
            o1.t[j] = f2bf(a * c1[j] - b * s1[j]);
            o2.t[j] = f2bf(b * c2[j] + a * s2[j]);
        }
        *(uint4*)(K + off)      = o1.v;
        *(uint4*)(K + off + 32) = o2.v;
    }
}

// ---------------------------------------------------------------------------
// Causal MFMA flash attention, v13 = v10 + exactly TWO single-purpose diffs:
//  (1) exp2f -> __builtin_amdgcn_exp2f (raw v_exp_f32; library exp2f is an
//      ocml call ~8-10 inst x32/tile = the bulk of the 61% VALUBusy).
//      [v11 had this too but bundled with a harmful hoist/unroll; the revert
//      threw out the good diff with the bad one]
//  (2) V swizzle depth d&7 -> d&15 (reader XOR l16<<3): kills the 4-way
//      bank conflict on PV ds_read_b64 (l16 vs l16+8 bank alias) -> 2-way
//      free. Store granularity 16B still respected (4-bit block XOR).
//  Everything else byte-identical to v10 (VGPR must stay 64).
// ---------------------------------------------------------------------------
__global__ __launch_bounds__(512, 2)
void attn_kernel(const u16* __restrict__ Q, const u16* __restrict__ K,
                 const u16* __restrict__ Vt, u16* __restrict__ O)
{
    const int id = blockIdx.x;
    const int xcd = id & 7, rr = id >> 3;   // rr in 0..127
    const int qb = 15 - (rr >> 3);          // monotone heavy -> light per XCD
    const int hb = xcd + 8 * (rr & 7);      // (b,h) pinned to one XCD
    const int h = hb & 15, b = hb >> 4;
    const int tid = threadIdx.x, lane = tid & 63, wave = tid >> 6;
    const int quad = lane >> 4, l16 = lane & 15;
    const int z3 = l16 & 7;

    __shared__ __align__(16) u16 Ks[2 * 8192];   // 32 KB dbuf [128 row][64 d] swz
    __shared__ __align__(16) u16 Vs[2 * 8192];   // 32 KB dbuf [64 d][128 t] swz

    // Q fragments in registers, pre-scaled by 0.125*log2(e) (log2-domain S)
    const u16* Qr = Q + ((size_t)(b * T_ + qb * 128 + wave * 16 + l16)) * D_ + h * HD_;
    bf16x8 qf[2];
    {
        const float qscale = 0.125f * 1.44269504f;
        union { u16 t[8]; bf16x8 v; } a, c;
#pragma unroll
        for (int ks = 0; ks < 2; ks++) {
            a.v = *(const bf16x8*)(Qr + ks * 32 + quad * 8);
#pragma unroll
            for (int j = 0; j < 8; j++) c.t[j] = f2bf(bf2f(a.t[j]) * qscale);
            qf[ks] = c.v;
        }
    }

    // ones B fragment for l-accum (16x16x16): B[k][0]=1 -> lanes l16==0 hold 1
    s16x4 ones4;
    {
        union { u16 t[4]; s16x4 v; } o;
        const u16 one = (l16 == 0) ? (u16)0x3F80 : (u16)0;
#pragma unroll
        for (int j = 0; j < 4; j++) o.t[j] = one;
        ones4 = o.v;
    }

    const u16* Kbase = K + ((size_t)(b * T_)) * D_ + h * HD_;
    const u16* Vbase = Vt + ((size_t)(b * H_ + h)) * HD_ * T_;

    f32x4 o_acc[4], o_l;
#pragma unroll
    for (int i = 0; i < 4; i++) o_acc[i] = (f32x4){0.f, 0.f, 0.f, 0.f};
    o_l = (f32x4){0.f, 0.f, 0.f, 0.f};
    float m_i = NEG_BIG;

    // per-lane K read bases (swizzled layout): row = ni*16+l16, block = (ks*4+quad)^z3
    const int kb0 = l16 * 64 + 8 * (quad ^ z3);
    const int kb1 = l16 * 64 + 8 * ((quad | 4) ^ z3);
    const int vsw = l16 << 3, vq = quad * 4;   // diff (2): 4-bit V swizzle

    const int nkb = qb + 1;

#define STAGE(KB, BSEL)                                                        \
    {                                                                          \
        const u16* Kg = Kbase + (size_t)(KB) * 128 * D_;                       \
        const u16* Vg = Vbase + (size_t)(KB) * 128;                            \
        u16* Kd = &Ks[(BSEL) * 8192];                                          \
        u16* Vd = &Vs[(BSEL) * 8192];                                          \
        _Pragma("unroll")                                                      \
        for (int i_ = 0; i_ < 2; i_++) {                                       \
            int idx = i_ * 512 + tid;                                          \
            /* K: row = idx>>3, blk = idx&7; src blk pre-swizzled */           \
            int kr = idx >> 3, kblk = idx & 7;                                 \
            async_copy16(Kg + (size_t)kr * D_ + ((kblk ^ (kr & 7)) * 8),       \
                         Kd + idx * 8);                                        \
            /* V: d-row = idx>>4, 8-elem src block pre-swizzled (4-bit) */     \
            int dv = idx >> 4, sv = idx & 15;                                  \
            async_copy16(Vg + (size_t)dv * T_ + 8 * (sv ^ (dv & 15)),          \
                         Vd + idx * 8);                                        \
        }                                                                      \
    }

    STAGE(0, 0);
    __syncthreads();   // drain prologue stage (vmcnt0 + barrier)

    int cur = 0;
    for (int kb = 0; kb < nkb; kb++) {
        if (kb + 1 < nkb) STAGE(kb + 1, cur ^ 1);   // prefetch overlaps compute

        const u16* Kc = &Ks[cur * 8192];
        const u16* Vc = &Vs[cur * 8192];

        // diagonal tile: wave covers qrows wave*16+[0,16) -> ni <= wave
        const int nLim = (kb == nkb - 1) ? (wave + 1) : 8;

        // S^T = K (Q*c)^T : lane holds q-row = l16, k-col = ni*16+quad*4+r
        f32x4 s[8];
#pragma unroll
        for (int ni = 0; ni < 8; ni++) s[ni] = (f32x4){0.f, 0.f, 0.f, 0.f};
        __builtin_amdgcn_s_setprio(1);
#pragma unroll
        for (int ni = 0; ni < 8; ni++)
            if (ni < nLim) {
                bf16x8 b0 = *(const bf16x8*)&Kc[kb0 + ni * 1024];
                s[ni] = __builtin_amdgcn_mfma_f32_16x16x32_bf16(b0, qf[0], s[ni], 0, 0, 0);
                bf16x8 b1 = *(const bf16x8*)&Kc[kb1 + ni * 1024];
                s[ni] = __builtin_amdgcn_mfma_f32_16x16x32_bf16(b1, qf[1], s[ni], 0, 0, 0);
            }
        __builtin_amdgcn_s_setprio(0);

        // diagonal masking (log2-domain values; comparisons unaffected)
        if (kb == nkb - 1) {
            const int qrow = qb * 128 + wave * 16 + l16;
            const int kc0 = kb * 128 + quad * 4;
#pragma unroll
            for (int ni = 0; ni < 8; ni++)
                if (ni < nLim)
#pragma unroll
                    for (int r = 0; r < 4; r++)
                        s[ni][r] = (kc0 + ni * 16 + r <= qrow) ? s[ni][r] : NEG_BIG;
        }

        // row max: per-ni max4, then tree over 8, then cross-quad
        float m8[8];
#pragma unroll
        for (int ni = 0; ni < 8; ni++)
            m8[ni] = (ni < nLim)
                ? fmaxf(fmaxf(s[ni][0], s[ni][1]), fmaxf(s[ni][2], s[ni][3]))
                : NEG_BIG;
        float mnew = fmaxf(fmaxf(fmaxf(m8[0], m8[1]), fmaxf(m8[2], m8[3])),
                           fmaxf(fmaxf(m8[4], m8[5]), fmaxf(m8[6], m8[7])));
        mnew = fmaxf(mnew, __shfl_xor(mnew, 16, 64));
        mnew = fmaxf(mnew, __shfl_xor(mnew, 32, 64));

        // defer-max: skip rescale entirely when no row's max grew (exact, THR=0)
        if (!__all(mnew <= m_i)) {
            float mo = m_i;
            m_i = fmaxf(m_i, mnew);
            float alpha = __builtin_amdgcn_exp2f(mo - m_i);
            const int asrc = quad * 20;   // lane l16 = quad*4+r within quad
            float a_o[4];
#pragma unroll
            for (int r = 0; r < 4; r++) a_o[r] = __shfl(alpha, asrc + r, 64);
#pragma unroll
            for (int i = 0; i < 4; i++)
#pragma unroll
                for (int r = 0; r < 4; r++) o_acc[i][r] *= a_o[r];
#pragma unroll
            for (int r = 0; r < 4; r++) o_l[r] *= a_o[r];
        }

        // P = exp2(S - m) packed to 16x16x16 A-fragments
        s16x4 pa[8];
#pragma unroll
        for (int ni = 0; ni < 8; ni++)
            if (ni < nLim) {
                union { u16 t[4]; s16x4 v; } c;
#pragma unroll
                for (int r = 0; r < 4; r++) {
                    float p = __builtin_amdgcn_exp2f(s[ni][r] - m_i);
                    union { __bf16 b; u16 u; } cv;
                    cv.b = (__bf16)p;
                    c.t[r] = cv.u;
                }
                pa[ni] = c.v;
            }

        // O += P V ; l += P * ones  (16x16x16 MFMA; V b64 from swizzled Vs)
        __builtin_amdgcn_s_setprio(1);
#pragma unroll
        for (int ni = 0; ni < 8; ni++)
            if (ni < nLim) {
#pragma unroll
                for (int d0i = 0; d0i < 4; d0i++) {
                    int uidx = (d0i * 16 + l16) * 128 + ((ni * 16 + vq) ^ vsw);
                    s16x4 vb = *(const s16x4*)&Vc[uidx];
                    o_acc[d0i] = __builtin_amdgcn_mfma_f32_16x16x16bf16_1k(
                        pa[ni], vb, o_acc[d0i], 0, 0, 0);
                }
                o_l = __builtin_amdgcn_mfma_f32_16x16x16bf16_1k(
                    pa[ni], ones4, o_l, 0, 0, 0);
            }
        __builtin_amdgcn_s_setprio(0);

        __syncthreads();   // reads of buf done + next stage drained
        cur ^= 1;
    }

    // l for output row quad*4+r sits at lane (same quad, l16=0), reg r
    float inv_o[4];
#pragma unroll
    for (int r = 0; r < 4; r++) {
        float lv = __shfl(o_l[r], lane & 48, 64);
        inv_o[r] = 1.f / fmaxf(lv, 1e-30f);
    }

    u16* Og = O + ((size_t)(b * T_ + qb * 128)) * D_ + h * HD_;
#pragma unroll
    for (int d0i = 0; d0i < 4; d0i++)
#pragma unroll
        for (int r = 0; r < 4; r++)
            Og[(size_t)(wave * 16 + quad * 4 + r) * D_ + d0i * 16 + l16] =
                f2bf(o_acc[d0i][r] * inv_o[r]);
#undef STAGE
}

// ---------------------------------------------------------------------------
// Workspace (u16 elements), 32M used (64 MiB):
//   ws [0,  8M): Qbuf; attn O aliases it (per-(row,col) read-then-write)
//   ws [8, 16M): Kbuf; after attn -> WtO at [8M, 9M)
//   ws [16,24M): Vbuf
//   ws [24,27M): WtQKV (dead after QKV gemm) -> Vtbuf [24M, 32M)
//   d_out:       first 16 MB = xb (bf16 x) until QKV gemm; then fp32 output
// ---------------------------------------------------------------------------
extern "C" void kernel_launch(void* const* d_in, const int* in_sizes, int n_in,
                              void* d_out, int out_size, void* d_ws, size_t ws_size,
                              hipStream_t stream)
{
    (void)in_sizes; (void)n_in; (void)out_size; (void)ws_size;
    const float* x    = (const float*)d_in[0];
    const float* cosb = (const float*)d_in[2];
    const float* sinb = (const float*)d_in[3];
    const float* Wq   = (const float*)d_in[4];
    const float* bq   = (const float*)d_in[5];
    const float* Wk   = (const float*)d_in[6];
    const float* bk   = (const float*)d_in[7];
    const float* Wv   = (const float*)d_in[8];
    const float* bv   = (const float*)d_in[9];
    const float* Wo   = (const float*)d_in[10];
    const float* bo   = (const float*)d_in[11];

    u16* ws = (u16*)d_ws;
    const size_t MD = (size_t)M_ * D_;
    u16* xb     = (u16*)d_out;
    u16* Qbuf   = ws;
    u16* Kbuf   = ws + MD;
    u16* Vbuf   = ws + 2 * MD;
    u16* WtQKV  = ws + 3 * MD;
    u16* Vtbuf  = ws + 3 * MD;
    u16* WtO    = ws + MD;
    u16* Abuf   = ws;

    convert_x<<<dim3(M_ * D_ / 2048), 256, 0, stream>>>(x, xb);
    transpose_w<<<dim3(16, 16, 3), 256, 0, stream>>>(Wq, Wk, Wv, WtQKV);
    gemm_bt<0><<<dim3(64, 8, 3), 256, 0, stream>>>(xb, WtQKV, bq, bk, bv,
                                                   Qbuf, M_, D_, D_);
    rope_qk<<<dim3((B_ * T_ * H_ * 4) / 256), 256, 0, stream>>>(
        Qbuf, Kbuf, cosb, sinb);
    transpose_v<<<dim3(32, 16, 4), 256, 0, stream>>>(Vbuf, Vtbuf);
    attn_kernel<<<dim3(1024), 512, 0, stream>>>(Qbuf, Kbuf, Vtbuf, Abuf);
    transpose_w<<<dim3(16, 16, 1), 256, 0, stream>>>(Wo, Wo, Wo, WtO);
    gemm_bt<1><<<dim3(64, 8, 1), 256, 0, stream>>>(Abuf, WtO, bo, bo, bo,
                                                   d_out, M_, D_, D_);
}

// Round 11
// 283.112 us; speedup vs baseline: 1.2367x; 1.0135x over previous
//
#include <hip/hip_runtime.h>
#include <math.h>

typedef unsigned short u16;
typedef unsigned int   u32;
typedef __bf16  bf16x8 __attribute__((ext_vector_type(8)));
typedef short   s16x4  __attribute__((ext_vector_type(4)));
typedef float   f32x4  __attribute__((ext_vector_type(4)));

#define B_  4
#define T_  2048
#define D_  1024
#define H_  16
#define HD_ 64
#define M_  (B_*T_)   // 8192
#define NEG_BIG (-30000.0f)

__device__ __forceinline__ float bf2f(u16 h) {
    u32 u = ((u32)h) << 16;
    return __uint_as_float(u);
}
__device__ __forceinline__ u16 f2bf(float f) {
    u32 u = __float_as_uint(f);
    u32 r = (u + 0x7fffu + ((u >> 16) & 1u)) >> 16;
    return (u16)r;
}
__device__ __forceinline__ void async_copy16(const u16* g, u16* l) {
    __builtin_amdgcn_global_load_lds(
        (const __attribute__((address_space(1))) u32*)g,
        (__attribute__((address_space(3))) u32*)l, 16, 0, 0);
}

// ---------------------------------------------------------------------------
// x (fp32) -> bf16, vectorized. 8 elements/thread.
// ---------------------------------------------------------------------------
__global__ __launch_bounds__(256)
void convert_x(const float* __restrict__ X, u16* __restrict__ Xb)
{
    const int id = (blockIdx.x * 256 + threadIdx.x) * 8;
    float4 f0 = *(const float4*)(X + id);
    float4 f1 = *(const float4*)(X + id + 4);
    union { u16 t[8]; uint4 v; } c;
    c.t[0] = f2bf(f0.x); c.t[1] = f2bf(f0.y); c.t[2] = f2bf(f0.z); c.t[3] = f2bf(f0.w);
    c.t[4] = f2bf(f1.x); c.t[5] = f2bf(f1.y); c.t[6] = f2bf(f1.z); c.t[7] = f2bf(f1.w);
    *(uint4*)(Xb + id) = c.v;
}

// ---------------------------------------------------------------------------
// QKV GEMM (bf16 out), BK=64 swizzled staging, XCD-affinity grid, and FUSED
// epilogues:
//   z<2 (Q,K): RoPE applied in-register (pairs (ni,ni+2) = (dd,dd+32) of one
//              head; same math as the old rope_qk kernel). Row-major store.
//   z=2 (V):   written TRANSPOSED directly to Vt[(b*H+h)*HD+dd][t] via 8B
//              packed stores (4 consecutive t per thread).
// Grid: 1536 1-D blocks; id -> xcd=id&7 keeps 8 m-panels (2 MB A) resident
// in each XCD's L2; consecutive same-XCD blocks share one B-panel.
// ---------------------------------------------------------------------------
__global__ __launch_bounds__(256)
void gemm_qkv(const u16* __restrict__ A, const u16* __restrict__ Bt_base,
              const float* __restrict__ bias0, const float* __restrict__ bias1,
              const float* __restrict__ bias2,
              const float* __restrict__ cosb, const float* __restrict__ sinb,
              u16* __restrict__ QK_base, u16* __restrict__ VtOut)
{
    const int id = blockIdx.x;
    const int xcd = id & 7, rr = id >> 3;
    const int m_blk = xcd * 8 + (rr & 7);
    const int rest = rr >> 3;
    const int n_blk = rest & 7;
    const int z = rest >> 3;
    const int m0 = m_blk * 128, n0 = n_blk * 128;
    const int K = D_, N = D_;

    const u16* Bt = Bt_base + (size_t)z * N * K;
    const float* bias = (z == 0) ? bias0 : ((z == 1) ? bias1 : bias2);

    const int tid = threadIdx.x, lane = tid & 63, wave = tid >> 6;
    const int wm = (wave >> 1) * 64, wn = (wave & 1) * 64;
    const int quad = lane >> 4, l16 = lane & 15;
    const int z3 = l16 & 7;

    __shared__ __align__(16) u16 As[128 * 64];
    __shared__ __align__(16) u16 Bs[128 * 64];

    const int c0 = 8 * (quad ^ z3);
    const int c1 = 8 * ((quad | 4) ^ z3);

    f32x4 acc[4][4];
#pragma unroll
    for (int i = 0; i < 4; i++)
#pragma unroll
        for (int j = 0; j < 4; j++) acc[i][j] = (f32x4){0.f, 0.f, 0.f, 0.f};

    for (int k0 = 0; k0 < K; k0 += 64) {
        __syncthreads();
#pragma unroll
        for (int i = 0; i < 4; i++) {
            int idx = i * 256 + tid;
            int r = idx >> 3;
            int sc = 8 * ((idx & 7) ^ (r & 7));
            async_copy16(A  + (size_t)(m0 + r) * K + k0 + sc, &As[idx * 8]);
            async_copy16(Bt + (size_t)(n0 + r) * K + k0 + sc, &Bs[idx * 8]);
        }
        __syncthreads();

#pragma unroll
        for (int ks = 0; ks < 2; ks++) {
            const int cc = ks ? c1 : c0;
            bf16x8 af[4], bfr[4];
#pragma unroll
            for (int mi = 0; mi < 4; mi++)
                af[mi] = *(const bf16x8*)&As[(wm + mi * 16 + l16) * 64 + cc];
#pragma unroll
            for (int ni = 0; ni < 4; ni++)
                bfr[ni] = *(const bf16x8*)&Bs[(wn + ni * 16 + l16) * 64 + cc];
#pragma unroll
            for (int mi = 0; mi < 4; mi++)
#pragma unroll
                for (int ni = 0; ni < 4; ni++)
                    acc[mi][ni] = __builtin_amdgcn_mfma_f32_16x16x32_bf16(
                        af[mi], bfr[ni], acc[mi][ni], 0, 0, 0);
        }
    }

    float bv[4];
#pragma unroll
    for (int ni = 0; ni < 4; ni++) bv[ni] = bias[n0 + wn + ni * 16 + l16];

    if (z < 2) {
        // --- Q/K path: fused RoPE, row-major bf16 store ---
        u16* Cz = QK_base + (size_t)z * M_ * N;
#pragma unroll
        for (int mi = 0; mi < 4; mi++) {
#pragma unroll
            for (int reg = 0; reg < 4; reg++) {
                int row = m0 + wm + mi * 16 + quad * 4 + reg;
                int t = row & (T_ - 1);
                const float* cr = cosb + (size_t)t * HD_;
                const float* sr = sinb + (size_t)t * HD_;
                u16* Crow = Cz + (size_t)row * N + n0 + wn;
#pragma unroll
                for (int ni = 0; ni < 2; ni++) {
                    int dd = ni * 16 + l16;          // < 32
                    float x1 = acc[mi][ni][reg] + bv[ni];
                    float x2 = acc[mi][ni + 2][reg] + bv[ni + 2];
                    float cc1 = cr[dd],      ss1 = sr[dd];
                    float cc2 = cr[dd + 32], ss2 = sr[dd + 32];
                    Crow[dd]      = f2bf(x1 * cc1 - x2 * ss1);
                    Crow[dd + 32] = f2bf(x2 * cc2 + x1 * ss2);
                }
            }
        }
    } else {
        // --- V path: transposed write Vt[(b*H+h)*HD+dd][t], 8B packed ---
        const int bb = m0 >> 11;   // batch (128-row tile never crosses b)
#pragma unroll
        for (int mi = 0; mi < 4; mi++) {
            int row0 = m0 + wm + mi * 16 + quad * 4;
            int t = row0 & (T_ - 1);
#pragma unroll
            for (int ni = 0; ni < 4; ni++) {
                int col = n0 + wn + ni * 16 + l16;
                int h = col >> 6, dd = col & 63;
                union { u16 t4[4]; uint2 v; } pk;
#pragma unroll
                for (int reg = 0; reg < 4; reg++)
                    pk.t4[reg] = f2bf(acc[mi][ni][reg] + bv[ni]);
                *(uint2*)(VtOut + ((size_t)(bb * H_ + h) * HD_ + dd) * T_ + t) = pk.v;
            }
        }
    }
}

// ---------------------------------------------------------------------------
// Output-projection GEMM (fp32 out), same core, XCD-affinity 1-D grid (512).
// ---------------------------------------------------------------------------
__global__ __launch_bounds__(256)
void gemm_proj(const u16* __restrict__ A, const u16* __restrict__ Bt,
               const float* __restrict__ bias,
               float* __restrict__ C, int M, int N, int K)
{
    const int id = blockIdx.x;
    const int xcd = id & 7, rr = id >> 3;
    const int m_blk = xcd * 8 + (rr & 7);
    const int n_blk = rr >> 3;
    const int m0 = m_blk * 128, n0 = n_blk * 128;

    const int tid = threadIdx.x, lane = tid & 63, wave = tid >> 6;
    const int wm = (wave >> 1) * 64, wn = (wave & 1) * 64;
    const int quad = lane >> 4, l16 = lane & 15;
    const int z3 = l16 & 7;

    __shared__ __align__(16) u16 As[128 * 64];
    __shared__ __align__(16) u16 Bs[128 * 64];

    const int c0 = 8 * (quad ^ z3);
    const int c1 = 8 * ((quad | 4) ^ z3);

    f32x4 acc[4][4];
#pragma unroll
    for (int i = 0; i < 4; i++)
#pragma unroll
        for (int j = 0; j < 4; j++) acc[i][j] = (f32x4){0.f, 0.f, 0.f, 0.f};

    for (int k0 = 0; k0 < K; k0 += 64) {
        __syncthreads();
#pragma unroll
        for (int i = 0; i < 4; i++) {
            int idx = i * 256 + tid;
            int r = idx >> 3;
            int sc = 8 * ((idx & 7) ^ (r & 7));
            async_copy16(A  + (size_t)(m0 + r) * K + k0 + sc, &As[idx * 8]);
            async_copy16(Bt + (size_t)(n0 + r) * K + k0 + sc, &Bs[idx * 8]);
        }
        __syncthreads();

#pragma unroll
        for (int ks = 0; ks < 2; ks++) {
            const int cc = ks ? c1 : c0;
            bf16x8 af[4], bfr[4];
#pragma unroll
            for (int mi = 0; mi < 4; mi++)
                af[mi] = *(const bf16x8*)&As[(wm + mi * 16 + l16) * 64 + cc];
#pragma unroll
            for (int ni = 0; ni < 4; ni++)
                bfr[ni] = *(const bf16x8*)&Bs[(wn + ni * 16 + l16) * 64 + cc];
#pragma unroll
            for (int mi = 0; mi < 4; mi++)
#pragma unroll
                for (int ni = 0; ni < 4; ni++)
                    acc[mi][ni] = __builtin_amdgcn_mfma_f32_16x16x32_bf16(
                        af[mi], bfr[ni], acc[mi][ni], 0, 0, 0);
        }
    }

    float bv[4];
#pragma unroll
    for (int ni = 0; ni < 4; ni++) bv[ni] = bias[n0 + wn + ni * 16 + l16];
#pragma unroll
    for (int mi = 0; mi < 4; mi++) {
#pragma unroll
        for (int reg = 0; reg < 4; reg++) {
            int row = m0 + wm + mi * 16 + quad * 4 + reg;
#pragma unroll
            for (int ni = 0; ni < 4; ni++) {
                int col = n0 + wn + ni * 16 + l16;
                C[(size_t)row * N + col] = acc[mi][ni][reg] + bv[ni];
            }
        }
    }
}

// ---------------------------------------------------------------------------
// Transpose + convert fp32 weight (D x D) -> bf16 Wt[n][k] = W[k][n].
// ---------------------------------------------------------------------------
__global__ __launch_bounds__(256)
void transpose_w(const float* __restrict__ w0, const float* __restrict__ w1,
                 const float* __restrict__ w2,
                 u16* __restrict__ out)
{
    const int z = blockIdx.z;
    const float* W = (z == 0) ? w0 : ((z == 1) ? w1 : w2);
    u16* Wt = out + (size_t)z * D_ * D_;
    const int k0 = blockIdx.x * 64, n0 = blockIdx.y * 64;
    __shared__ u16 tl[64][72];
    const int tid = threadIdx.x;
    const int r = tid >> 2, c4 = (tid & 3) * 16;
#pragma unroll
    for (int j = 0; j < 4; j++) {
        float4 fv = *(const float4*)(W + (size_t)(k0 + r) * D_ + n0 + c4 + j * 4);
        tl[r][c4 + j * 4 + 0] = f2bf(fv.x);
        tl[r][c4 + j * 4 + 1] = f2bf(fv.y);
        tl[r][c4 + j * 4 + 2] = f2bf(fv.z);
        tl[r][c4 + j * 4 + 3] = f2bf(fv.w);
    }
    __syncthreads();
    u16 vals[16];
#pragma unroll
    for (int j = 0; j < 16; j++) vals[j] = tl[c4 + j][r];
#pragma unroll
    for (int j = 0; j < 2; j++)
        *(uint4*)(Wt + (size_t)(n0 + r) * D_ + k0 + c4 + j * 8) =
            *(const uint4*)&vals[j * 8];
}

// ---------------------------------------------------------------------------
// Causal MFMA flash attention, v13 (74.8 us verified) — UNCHANGED.
// ---------------------------------------------------------------------------
__global__ __launch_bounds__(512, 2)
void attn_kernel(const u16* __restrict__ Q, const u16* __restrict__ K,
                 const u16* __restrict__ Vt, u16* __restrict__ O)
{
    const int id = blockIdx.x;
    const int xcd = id & 7, rr = id >> 3;   // rr in 0..127
    const int qb = 15 - (rr >> 3);          // monotone heavy -> light per XCD
    const int hb = xcd + 8 * (rr & 7);      // (b,h) pinned to one XCD
    const int h = hb & 15, b = hb >> 4;
    const int tid = threadIdx.x, lane = tid & 63, wave = tid >> 6;
    const int quad = lane >> 4, l16 = lane & 15;
    const int z3 = l16 & 7;

    __shared__ __align__(16) u16 Ks[2 * 8192];   // 32 KB dbuf [128 row][64 d] swz
    __shared__ __align__(16) u16 Vs[2 * 8192];   // 32 KB dbuf [64 d][128 t] swz

    // Q fragments in registers, pre-scaled by 0.125*log2(e) (log2-domain S)
    const u16* Qr = Q + ((size_t)(b * T_ + qb * 128 + wave * 16 + l16)) * D_ + h * HD_;
    bf16x8 qf[2];
    {
        const float qscale = 0.125f * 1.44269504f;
        union { u16 t[8]; bf16x8 v; } a, c;
#pragma unroll
        for (int ks = 0; ks < 2; ks++) {
            a.v = *(const bf16x8*)(Qr + ks * 32 + quad * 8);
#pragma unroll
            for (int j = 0; j < 8; j++) c.t[j] = f2bf(bf2f(a.t[j]) * qscale);
            qf[ks] = c.v;
        }
    }

    // ones B fragment for l-accum (16x16x16): B[k][0]=1 -> lanes l16==0 hold 1
    s16x4 ones4;
    {
        union { u16 t[4]; s16x4 v; } o;
        const u16 one = (l16 == 0) ? (u16)0x3F80 : (u16)0;
#pragma unroll
        for (int j = 0; j < 4; j++) o.t[j] = one;
        ones4 = o.v;
    }

    const u16* Kbase = K + ((size_t)(b * T_)) * D_ + h * HD_;
    const u16* Vbase = Vt + ((size_t)(b * H_ + h)) * HD_ * T_;

    f32x4 o_acc[4], o_l;
#pragma unroll
    for (int i = 0; i < 4; i++) o_acc[i] = (f32x4){0.f, 0.f, 0.f, 0.f};
    o_l = (f32x4){0.f, 0.f, 0.f, 0.f};
    float m_i = NEG_BIG;

    // per-lane K read bases (swizzled layout): row = ni*16+l16, block = (ks*4+quad)^z3
    const int kb0 = l16 * 64 + 8 * (quad ^ z3);
    const int kb1 = l16 * 64 + 8 * ((quad | 4) ^ z3);
    const int vsw = l16 << 3, vq = quad * 4;

    const int nkb = qb + 1;

#define STAGE(KB, BSEL)                                                        \
    {                                                                          \
        const u16* Kg = Kbase + (size_t)(KB) * 128 * D_;                       \
        const u16* Vg = Vbase + (size_t)(KB) * 128;                            \
        u16* Kd = &Ks[(BSEL) * 8192];                                          \
        u16* Vd = &Vs[(BSEL) * 8192];                                          \
        _Pragma("unroll")                                                      \
        for (int i_ = 0; i_ < 2; i_++) {                                       \
            int idx = i_ * 512 + tid;                                          \
            int kr = idx >> 3, kblk = idx & 7;                                 \
            async_copy16(Kg + (size_t)kr * D_ + ((kblk ^ (kr & 7)) * 8),       \
                         Kd + idx * 8);                                        \
            int dv = idx >> 4, sv = idx & 15;                                  \
            async_copy16(Vg + (size_t)dv * T_ + 8 * (sv ^ (dv & 15)),          \
                         Vd + idx * 8);                                        \
        }                                                                      \
    }

    STAGE(0, 0);
    __syncthreads();   // drain prologue stage (vmcnt0 + barrier)

    int cur = 0;
    for (int kb = 0; kb < nkb; kb++) {
        if (kb + 1 < nkb) STAGE(kb + 1, cur ^ 1);   // prefetch overlaps compute

        const u16* Kc = &Ks[cur * 8192];
        const u16* Vc = &Vs[cur * 8192];

        // diagonal tile: wave covers qrows wave*16+[0,16) -> ni <= wave
        const int nLim = (kb == nkb - 1) ? (wave + 1) : 8;

        // S^T = K (Q*c)^T : lane holds q-row = l16, k-col = ni*16+quad*4+r
        f32x4 s[8];
#pragma unroll
        for (int ni = 0; ni < 8; ni++) s[ni] = (f32x4){0.f, 0.f, 0.f, 0.f};
        __builtin_amdgcn_s_setprio(1);
#pragma unroll
        for (int ni = 0; ni < 8; ni++)
            if (ni < nLim) {
                bf16x8 b0 = *(const bf16x8*)&Kc[kb0 + ni * 1024];
                s[ni] = __builtin_amdgcn_mfma_f32_16x16x32_bf16(b0, qf[0], s[ni], 0, 0, 0);
                bf16x8 b1 = *(const bf16x8*)&Kc[kb1 + ni * 1024];
                s[ni] = __builtin_amdgcn_mfma_f32_16x16x32_bf16(b1, qf[1], s[ni], 0, 0, 0);
            }
        __builtin_amdgcn_s_setprio(0);

        // diagonal masking (log2-domain values; comparisons unaffected)
        if (kb == nkb - 1) {
            const int qrow = qb * 128 + wave * 16 + l16;
            const int kc0 = kb * 128 + quad * 4;
#pragma unroll
            for (int ni = 0; ni < 8; ni++)
                if (ni < nLim)
#pragma unroll
                    for (int r = 0; r < 4; r++)
                        s[ni][r] = (kc0 + ni * 16 + r <= qrow) ? s[ni][r] : NEG_BIG;
        }

        // row max: per-ni max4, then tree over 8, then cross-quad
        float m8[8];
#pragma unroll
        for (int ni = 0; ni < 8; ni++)
            m8[ni] = (ni < nLim)
                ? fmaxf(fmaxf(s[ni][0], s[ni][1]), fmaxf(s[ni][2], s[ni][3]))
                : NEG_BIG;
        float mnew = fmaxf(fmaxf(fmaxf(m8[0], m8[1]), fmaxf(m8[2], m8[3])),
                           fmaxf(fmaxf(m8[4], m8[5]), fmaxf(m8[6], m8[7])));
        mnew = fmaxf(mnew, __shfl_xor(mnew, 16, 64));
        mnew = fmaxf(mnew, __shfl_xor(mnew, 32, 64));

        // defer-max: skip rescale entirely when no row's max grew (exact, THR=0)
        if (!__all(mnew <= m_i)) {
            float mo = m_i;
            m_i = fmaxf(m_i, mnew);
            float alpha = __builtin_amdgcn_exp2f(mo - m_i);
            const int asrc = quad * 20;   // lane l16 = quad*4+r within quad
            float a_o[4];
#pragma unroll
            for (int r = 0; r < 4; r++) a_o[r] = __shfl(alpha, asrc + r, 64);
#pragma unroll
            for (int i = 0; i < 4; i++)
#pragma unroll
                for (int r = 0; r < 4; r++) o_acc[i][r] *= a_o[r];
#pragma unroll
            for (int r = 0; r < 4; r++) o_l[r] *= a_o[r];
        }

        // P = exp2(S - m) packed to 16x16x16 A-fragments
        s16x4 pa[8];
#pragma unroll
        for (int ni = 0; ni < 8; ni++)
            if (ni < nLim) {
                union { u16 t[4]; s16x4 v; } c;
#pragma unroll
                for (int r = 0; r < 4; r++) {
                    float p = __builtin_amdgcn_exp2f(s[ni][r] - m_i);
                    union { __bf16 b; u16 u; } cv;
                    cv.b = (__bf16)p;
                    c.t[r] = cv.u;
                }
                pa[ni] = c.v;
            }

        // O += P V ; l += P * ones  (16x16x16 MFMA; V b64 from swizzled Vs)
        __builtin_amdgcn_s_setprio(1);
#pragma unroll
        for (int ni = 0; ni < 8; ni++)
            if (ni < nLim) {
#pragma unroll
                for (int d0i = 0; d0i < 4; d0i++) {
                    int uidx = (d0i * 16 + l16) * 128 + ((ni * 16 + vq) ^ vsw);
                    s16x4 vb = *(const s16x4*)&Vc[uidx];
                    o_acc[d0i] = __builtin_amdgcn_mfma_f32_16x16x16bf16_1k(
                        pa[ni], vb, o_acc[d0i], 0, 0, 0);
                }
                o_l = __builtin_amdgcn_mfma_f32_16x16x16bf16_1k(
                    pa[ni], ones4, o_l, 0, 0, 0);
            }
        __builtin_amdgcn_s_setprio(0);

        __syncthreads();   // reads of buf done + next stage drained
        cur ^= 1;
    }

    // l for output row quad*4+r sits at lane (same quad, l16=0), reg r
    float inv_o[4];
#pragma unroll
    for (int r = 0; r < 4; r++) {
        float lv = __shfl(o_l[r], lane & 48, 64);
        inv_o[r] = 1.f / fmaxf(lv, 1e-30f);
    }

    u16* Og = O + ((size_t)(b * T_ + qb * 128)) * D_ + h * HD_;
#pragma unroll
    for (int d0i = 0; d0i < 4; d0i++)
#pragma unroll
        for (int r = 0; r < 4; r++)
            Og[(size_t)(wave * 16 + quad * 4 + r) * D_ + d0i * 16 + l16] =
                f2bf(o_acc[d0i][r] * inv_o[r]);
#undef STAGE
}

// ---------------------------------------------------------------------------
// Workspace (u16 elements):
//   ws [0,  8M): Qbuf (roped); attn O aliases it
//   ws [8, 16M): Kbuf (roped); after attn -> WtO
//   ws [16,24M): Vt (written transposed by gemm_qkv z=2)
//   ws [24,27M): WtQKV
//   d_out:       first 16 MB = xb (bf16 x) until QKV gemm; then fp32 output
// ---------------------------------------------------------------------------
extern "C" void kernel_launch(void* const* d_in, const int* in_sizes, int n_in,
                              void* d_out, int out_size, void* d_ws, size_t ws_size,
                              hipStream_t stream)
{
    (void)in_sizes; (void)n_in; (void)out_size; (void)ws_size;
    const float* x    = (const float*)d_in[0];
    const float* cosb = (const float*)d_in[2];
    const float* sinb = (const float*)d_in[3];
    const float* Wq   = (const float*)d_in[4];
    const float* bq   = (const float*)d_in[5];
    const float* Wk   = (const float*)d_in[6];
    const float* bk   = (const float*)d_in[7];
    const float* Wv   = (const float*)d_in[8];
    const float* bv   = (const float*)d_in[9];
    const float* Wo   = (const float*)d_in[10];
    const float* bo   = (const float*)d_in[11];

    u16* ws = (u16*)d_ws;
    const size_t MD = (size_t)M_ * D_;
    u16* xb     = (u16*)d_out;
    u16* Qbuf   = ws;            // Q at +0, K at +MD (gemm_qkv z<2)
    u16* Kbuf   = ws + MD;
    u16* Vtbuf  = ws + 2 * MD;   // transposed V from gemm_qkv z=2
    u16* WtQKV  = ws + 3 * MD;
    u16* WtO    = ws + MD;       // aliases Kbuf after attn
    u16* Abuf   = ws;            // attn output aliases Qbuf
    (void)Kbuf;

    convert_x<<<dim3(M_ * D_ / 2048), 256, 0, stream>>>(x, xb);
    transpose_w<<<dim3(16, 16, 3), 256, 0, stream>>>(Wq, Wk, Wv, WtQKV);
    gemm_qkv<<<dim3(1536), 256, 0, stream>>>(xb, WtQKV, bq, bk, bv,
                                             cosb, sinb, Qbuf, Vtbuf);
    attn_kernel<<<dim3(1024), 512, 0, stream>>>(Qbuf, ws + MD, Vtbuf, Abuf);
    transpose_w<<<dim3(16, 16, 1), 256, 0, stream>>>(Wo, Wo, Wo, WtO);
    gemm_proj<<<dim3(512), 256, 0, stream>>>(Abuf, WtO, bo,
                                             (float*)d_out, M_, D_, D_);
}